// Round 1
// baseline (1309.178 us; speedup 1.0000x reference)
//
#include <hip/hip_runtime.h>

// ---------------------------------------------------------------------------
// MLA prefill: q = rms(x Wqa^T) Wqb^T ; kv = x Wkva^T ; ckv = rms(kv[:512]) ;
// k_nope = ckv Wkb^T ; v = ckv Wvb^T ; rope(q_pe), rope(k_pe) ;
// flash attention (192-d QK, 128-d V, causal) ; out = attn Wo^T
// All matmuls: bf16 MFMA 16x16x32, fp32 accum. Workspace ~114 MiB w/ aliasing.
// ---------------------------------------------------------------------------

typedef __bf16 bf16;
typedef __bf16 bf16x8 __attribute__((ext_vector_type(8)));
typedef float floatx4 __attribute__((ext_vector_type(4)));

#define HH     16
#define DNOPE  128
#define DROPE  64
#define DV     128
#define DQK    192        // NOPE + ROPE
#define HID    2048
#define QLR    1536
#define KVLR   512
#define BB     4
#define SS     1024
#define NTOK   4096       // BB*SS
#define EPSF   1e-6f

// ---------------- helpers ----------------
__device__ inline void cvt_store4(bf16* dst, float a, float b, float c, float d) {
  union { bf16 h[4]; uint2 u; } t;
  t.h[0] = (bf16)a; t.h[1] = (bf16)b; t.h[2] = (bf16)c; t.h[3] = (bf16)d;
  *(uint2*)dst = t.u;
}

__device__ inline void load_row4(const float* __restrict__ A, size_t off, bool ok, bf16* dst) {
  if (ok) {
    float4 v = *(const float4*)(A + off);
    cvt_store4(dst, v.x, v.y, v.z, v.w);
  } else {
    *(uint2*)dst = make_uint2(0u, 0u);
  }
}
__device__ inline void load_row4(const bf16* __restrict__ A, size_t off, bool ok, bf16* dst) {
  if (ok) *(uint2*)dst = *(const uint2*)(A + off);
  else    *(uint2*)dst = make_uint2(0u, 0u);
}

// ---------------- generic GEMM: C[M,N] = A[M,K] @ Bw[N,K]^T ----------------
// 128x128 block tile, 4 waves each 64x64 (4x4 MFMA 16x16x32 tiles), BK=32.
template <typename TA, typename TC>
__global__ __launch_bounds__(256) void gemm_bt(
    const TA* __restrict__ A, const float* __restrict__ Bw, TC* __restrict__ C,
    int M, int N, int K) {
  __shared__ bf16 As[128][40];   // pad 32->40: row stride 80B = 20 banks (2-way, free)
  __shared__ bf16 Bs[128][40];
  const int tid  = threadIdx.x;
  const int m0   = blockIdx.x << 7;
  const int n0   = blockIdx.y << 7;
  const int wave = tid >> 6, lane = tid & 63;
  const int wm   = (wave >> 1) << 6;   // 0 or 64
  const int wn   = (wave & 1) << 6;
  const int quad = lane >> 4, l16 = lane & 15;
  const int lr   = tid >> 3;           // 0..31 (row within pass)
  const int lc   = (tid & 7) << 2;     // 0..28 step 4

  floatx4 acc[4][4];
#pragma unroll
  for (int i = 0; i < 4; i++)
#pragma unroll
    for (int j = 0; j < 4; j++) acc[i][j] = floatx4{0.f, 0.f, 0.f, 0.f};

  for (int k0 = 0; k0 < K; k0 += 32) {
    __syncthreads();
#pragma unroll
    for (int p = 0; p < 4; p++) {
      int r = (p << 5) + lr;
      load_row4(A,  (size_t)(m0 + r) * K + k0 + lc, (m0 + r) < M, &As[r][lc]);
      load_row4(Bw, (size_t)(n0 + r) * K + k0 + lc, (n0 + r) < N, &Bs[r][lc]);
    }
    __syncthreads();
    bf16x8 af[4], bfr[4];
#pragma unroll
    for (int i = 0; i < 4; i++) af[i]  = *(const bf16x8*)&As[wm + (i << 4) + l16][quad << 3];
#pragma unroll
    for (int j = 0; j < 4; j++) bfr[j] = *(const bf16x8*)&Bs[wn + (j << 4) + l16][quad << 3];
#pragma unroll
    for (int i = 0; i < 4; i++)
#pragma unroll
      for (int j = 0; j < 4; j++)
        acc[i][j] = __builtin_amdgcn_mfma_f32_16x16x32_bf16(af[i], bfr[j], acc[i][j], 0, 0, 0);
  }

#pragma unroll
  for (int i = 0; i < 4; i++)
#pragma unroll
    for (int j = 0; j < 4; j++)
#pragma unroll
      for (int r = 0; r < 4; r++) {
        int gm = m0 + wm + (i << 4) + (quad << 2) + r;   // C/D: row = quad*4+reg
        int gn = n0 + wn + (j << 4) + l16;               //      col = lane&15
        if (gm < M && gn < N) C[(size_t)gm * N + gn] = (TC)acc[i][j][r];
      }
}

// ---------------- rmsnorm (row-wise) fp32 -> bf16 ----------------
__global__ __launch_bounds__(256) void rmsnorm_cast(
    const float* __restrict__ in, int istride, const float* __restrict__ w,
    bf16* __restrict__ out, int L) {
  const int row = blockIdx.x;
  const float* p = in + (size_t)row * istride;
  float ss = 0.f;
  for (int c = threadIdx.x; c < L; c += 256) { float v = p[c]; ss += v * v; }
#pragma unroll
  for (int off = 32; off > 0; off >>= 1) ss += __shfl_down(ss, off);
  __shared__ float red[4];
  if ((threadIdx.x & 63) == 0) red[threadIdx.x >> 6] = ss;
  __syncthreads();
  float tot = red[0] + red[1] + red[2] + red[3];
  float rs = rsqrtf(tot / (float)L + EPSF);
  for (int c = threadIdx.x; c < L; c += 256)
    out[(size_t)row * L + c] = (bf16)(p[c] * rs * w[c]);
}

// ---------------- rope (interleaved) ----------------
__global__ void rope_q(float* __restrict__ q, const float* __restrict__ sin_t,
                       const float* __restrict__ cos_t) {
  int idx = blockIdx.x * 256 + threadIdx.x;   // NTOK*HH*32 exactly
  int i = idx & 31;
  int h = (idx >> 5) & 15;
  int row = idx >> 9;
  int pos = row & (SS - 1);
  float* base = q + ((size_t)row * HH + h) * DQK + DNOPE + 2 * i;
  float e = base[0], o = base[1];
  float c = cos_t[pos * 32 + i], s = sin_t[pos * 32 + i];
  base[0] = e * c - o * s;
  base[1] = e * s + o * c;
}

__global__ void rope_k(const float* __restrict__ kv, const float* __restrict__ sin_t,
                       const float* __restrict__ cos_t, float* __restrict__ kpe) {
  int idx = blockIdx.x * 256 + threadIdx.x;   // NTOK*32 exactly
  int i = idx & 31;
  int row = idx >> 5;
  int pos = row & (SS - 1);
  const float* src = kv + (size_t)row * (KVLR + DROPE) + KVLR + 2 * i;
  float e = src[0], o = src[1];
  float c = cos_t[pos * 32 + i], s = sin_t[pos * 32 + i];
  kpe[(size_t)row * DROPE + 2 * i]     = e * c - o * s;
  kpe[(size_t)row * DROPE + 2 * i + 1] = e * s + o * c;
}

// ---------------- flash attention ----------------
// grid (S/64, H, B), 256 threads = 4 waves; wave w owns q rows [w*16, w*16+16).
// Q-tile 64x192 loaded once; per key-tile (64): QK^T (6 MFMA/ktile-subtile),
// online softmax (quad-local shfl), P -> LDS (A-layout), PV with V^T in LDS.
__global__ __launch_bounds__(256) void attn_kernel(
    const float* __restrict__ q, const bf16* __restrict__ knope,
    const float* __restrict__ kpe, const bf16* __restrict__ v,
    bf16* __restrict__ out) {
  const int q0 = blockIdx.x << 6;
  const int h  = blockIdx.y;
  const int b  = blockIdx.z;
  __shared__ bf16 Qs[64][200];    // 192 pad->200: stride 400B (2-way banks, free)
  __shared__ bf16 Ks[64][200];
  __shared__ bf16 Vts[128][72];   // transposed V: Vts[vd][key]
  __shared__ bf16 Ps[4][16][72];  // per-wave P tile 16x64 (pad 72)
  const int tid = threadIdx.x;
  const int wave = tid >> 6, lane = tid & 63;
  const int quad = lane >> 4, l16 = lane & 15;

  // stage Q tile (64 x 192) fp32 -> bf16
  for (int i = tid; i < 64 * 48; i += 256) {
    int r = i / 48, c4 = (i % 48) << 2;
    float4 vv = *(const float4*)(q + ((size_t)(b * SS + q0 + r) * HH + h) * DQK + c4);
    cvt_store4(&Qs[r][c4], vv.x, vv.y, vv.z, vv.w);
  }

  floatx4 acc_o[8];
#pragma unroll
  for (int n = 0; n < 8; n++) acc_o[n] = floatx4{0.f, 0.f, 0.f, 0.f};
  float m_i[4], l_i[4];
#pragma unroll
  for (int r = 0; r < 4; r++) { m_i[r] = -1e30f; l_i[r] = 0.f; }

  const float scale = 0.07216878364870323f;   // 1/sqrt(192)
  const int ktiles = (q0 >> 6) + 1;           // causal

  for (int kt = 0; kt < ktiles; kt++) {
    const int k0 = kt << 6;
    __syncthreads();   // prev iter LDS reads done
    // stage K tile: cols 0..127 from k_nope (bf16), 128..191 from k_pe (fp32)
    for (int i = tid; i < 64 * 32; i += 256) {
      int r = i >> 5, c4 = (i & 31) << 2;
      *(uint2*)&Ks[r][c4] =
          *(const uint2*)(knope + ((size_t)(b * SS + k0 + r) * HH + h) * DNOPE + c4);
    }
    for (int i = tid; i < 64 * 16; i += 256) {
      int r = i >> 4, c4 = (i & 15) << 2;
      float4 vv = *(const float4*)(kpe + (size_t)(b * SS + k0 + r) * DROPE + c4);
      cvt_store4(&Ks[r][DNOPE + c4], vv.x, vv.y, vv.z, vv.w);
    }
    // stage V transposed
    for (int i = tid; i < 64 * 32; i += 256) {
      int r = i >> 5, c4 = (i & 31) << 2;
      uint2 raw = *(const uint2*)(v + ((size_t)(b * SS + k0 + r) * HH + h) * DV + c4);
      const bf16* sp = (const bf16*)&raw;
      Vts[c4 + 0][r] = sp[0]; Vts[c4 + 1][r] = sp[1];
      Vts[c4 + 2][r] = sp[2]; Vts[c4 + 3][r] = sp[3];
    }
    __syncthreads();

    // QK^T : wave computes 16 (q) x 64 (k) scores
    bf16x8 aq[6];
#pragma unroll
    for (int t = 0; t < 6; t++)
      aq[t] = *(const bf16x8*)&Qs[(wave << 4) + l16][(t << 5) + (quad << 3)];
    floatx4 sacc[4];
#pragma unroll
    for (int kn = 0; kn < 4; kn++) {
      floatx4 s = floatx4{0.f, 0.f, 0.f, 0.f};
#pragma unroll
      for (int t = 0; t < 6; t++) {
        bf16x8 bk = *(const bf16x8*)&Ks[(kn << 4) + l16][(t << 5) + (quad << 3)];
        s = __builtin_amdgcn_mfma_f32_16x16x32_bf16(aq[t], bk, s, 0, 0, 0);
      }
      sacc[kn] = s;
    }

    // scale + causal mask + online softmax
    float pv[4][4];          // [kn][r]
    float mtile[4];
#pragma unroll
    for (int r = 0; r < 4; r++) mtile[r] = -1e30f;
#pragma unroll
    for (int kn = 0; kn < 4; kn++)
#pragma unroll
      for (int r = 0; r < 4; r++) {
        int qg = q0 + (wave << 4) + (quad << 2) + r;
        int kg = k0 + (kn << 4) + l16;
        float sv = sacc[kn][r] * scale;
        if (kg > qg) sv = -1e30f;
        pv[kn][r] = sv;
        mtile[r] = fmaxf(mtile[r], sv);
      }
#pragma unroll
    for (int r = 0; r < 4; r++) {
#pragma unroll
      for (int off = 1; off < 16; off <<= 1)
        mtile[r] = fmaxf(mtile[r], __shfl_xor(mtile[r], off));
    }
    float alpha[4];
#pragma unroll
    for (int r = 0; r < 4; r++) {
      float mnew = fmaxf(m_i[r], mtile[r]);
      alpha[r] = __expf(m_i[r] - mnew);
      m_i[r] = mnew;
      float part = 0.f;
#pragma unroll
      for (int kn = 0; kn < 4; kn++) {
        float p = __expf(pv[kn][r] - mnew);
        pv[kn][r] = p;
        part += p;
      }
#pragma unroll
      for (int off = 1; off < 16; off <<= 1) part += __shfl_xor(part, off);
      l_i[r] = l_i[r] * alpha[r] + part;
    }
    // write P (C-layout -> LDS so it can be re-read in A-layout)
#pragma unroll
    for (int kn = 0; kn < 4; kn++)
#pragma unroll
      for (int r = 0; r < 4; r++)
        Ps[wave][(quad << 2) + r][(kn << 4) + l16] = (bf16)pv[kn][r];
    // rescale O
#pragma unroll
    for (int n = 0; n < 8; n++)
#pragma unroll
      for (int r = 0; r < 4; r++) acc_o[n][r] *= alpha[r];
    __syncthreads();

    // PV: P(16x64) @ V(64x128)
    bf16x8 ap[2];
#pragma unroll
    for (int t = 0; t < 2; t++)
      ap[t] = *(const bf16x8*)&Ps[wave][l16][(t << 5) + (quad << 3)];
#pragma unroll
    for (int n = 0; n < 8; n++) {
#pragma unroll
      for (int t = 0; t < 2; t++) {
        bf16x8 bv = *(const bf16x8*)&Vts[(n << 4) + l16][(t << 5) + (quad << 3)];
        acc_o[n] = __builtin_amdgcn_mfma_f32_16x16x32_bf16(ap[t], bv, acc_o[n], 0, 0, 0);
      }
    }
  }

  // epilogue: O / l  -> out (NTOK, H, DV) bf16
#pragma unroll
  for (int r = 0; r < 4; r++) {
    float inv = 1.f / l_i[r];
    int qg = b * SS + q0 + (wave << 4) + (quad << 2) + r;
#pragma unroll
    for (int n = 0; n < 8; n++)
      out[((size_t)qg * HH + h) * DV + (n << 4) + l16] = (bf16)(acc_o[n][r] * inv);
  }
}

// ---------------- launch ----------------
extern "C" void kernel_launch(void* const* d_in, const int* in_sizes, int n_in,
                              void* d_out, int out_size, void* d_ws, size_t ws_size,
                              hipStream_t stream) {
  (void)in_sizes; (void)n_in; (void)out_size; (void)ws_size;
  const float* x       = (const float*)d_in[0];
  const float* wq_a    = (const float*)d_in[1];
  const float* w_qa_ln = (const float*)d_in[2];
  const float* wq_b    = (const float*)d_in[3];
  const float* wkv_a   = (const float*)d_in[4];
  const float* w_kva_ln= (const float*)d_in[5];
  const float* wk_b    = (const float*)d_in[6];
  const float* wv_b    = (const float*)d_in[7];
  const float* wo      = (const float*)d_in[8];
  const float* rsin    = (const float*)d_in[9];
  const float* rcos    = (const float*)d_in[10];
  float* out = (float*)d_out;

  // workspace layout (bytes), liveness-aliased; requires >= ~119.6 MB
  char* ws = (char*)d_ws;
  float* q     = (float*)(ws + 0);            // 4096x3072 f32   [0, 50331648)
  float* qlat  = (float*)(ws + 50331648);     // 4096x1536 f32   (dead after rms)
  bf16*  qln   = (bf16*) (ws + 75497472);     // 4096x1536 bf16  (dead after q gemm)
  bf16*  knope = (bf16*) (ws + 50331648);     // 4096x2048 bf16  (aliases qlat)
  bf16*  vbuf  = (bf16*) (ws + 67108864);     // 4096x2048 bf16  (aliases qlat/qln tail)
  float* kv    = (float*)(ws + 88080384);     // 4096x576  f32
  bf16*  ckv   = (bf16*) (ws + 97517568);     // 4096x512  bf16
  float* kpe   = (float*)(ws + 101711872);    // 4096x64   f32
  bf16*  attn  = (bf16*) (ws + 102760448);    // 4096x2048 bf16  -> ends 119537664

  dim3 blk(256);
  // q_lat = x @ wq_a^T
  gemm_bt<float, float><<<dim3(32, 12), blk, 0, stream>>>(x, wq_a, qlat, NTOK, QLR, HID);
  // q_ln = rmsnorm(q_lat) * w_qa_ln  (bf16)
  rmsnorm_cast<<<NTOK, blk, 0, stream>>>(qlat, QLR, w_qa_ln, qln, QLR);
  // q = q_ln @ wq_b^T  (fp32, rope applied in place later)
  gemm_bt<bf16, float><<<dim3(32, 24), blk, 0, stream>>>(qln, wq_b, q, NTOK, HH * DQK, QLR);
  // kv = x @ wkv_a^T
  gemm_bt<float, float><<<dim3(32, 5), blk, 0, stream>>>(x, wkv_a, kv, NTOK, KVLR + DROPE, HID);
  // ckv = rmsnorm(kv[:, :512]) (bf16)
  rmsnorm_cast<<<NTOK, blk, 0, stream>>>(kv, KVLR + DROPE, w_kva_ln, ckv, KVLR);
  // k_pe = rope(kv[:, 512:576])
  rope_k<<<NTOK * 32 / 256, blk, 0, stream>>>(kv, rsin, rcos, kpe);
  // rope q_pe in place
  rope_q<<<NTOK * HH * 32 / 256, blk, 0, stream>>>(q, rsin, rcos);
  // k_nope = ckv @ wk_b^T (bf16)
  gemm_bt<bf16, bf16><<<dim3(32, 16), blk, 0, stream>>>(ckv, wk_b, knope, NTOK, HH * DNOPE, KVLR);
  // v = ckv @ wv_b^T (bf16)
  gemm_bt<bf16, bf16><<<dim3(32, 16), blk, 0, stream>>>(ckv, wv_b, vbuf, NTOK, HH * DV, KVLR);
  // flash attention
  attn_kernel<<<dim3(SS / 64, HH, BB), blk, 0, stream>>>(q, knope, kpe, vbuf, attn);
  // out = attn @ wo^T (fp32)
  gemm_bt<bf16, float><<<dim3(32, 16), blk, 0, stream>>>(attn, wo, out, NTOK, HID, HID);
}

// Round 2
// 588.875 us; speedup vs baseline: 2.2232x; 2.2232x over previous
//
#include <hip/hip_runtime.h>
#include <stdint.h>

typedef __bf16 bf16;
typedef __bf16 bf16x8 __attribute__((ext_vector_type(8)));
typedef float floatx4 __attribute__((ext_vector_type(4)));

#define HH     16
#define DNOPE  128
#define DROPE  64
#define DV     128
#define DQK    192
#define HID    2048
#define QLR    1536
#define KVLR   512
#define BB     4
#define SS     1024
#define NTOK   4096
#define EPSF   1e-6f

// ---------------- helpers ----------------
__device__ inline void cvt_store4(bf16* dst, float a, float b, float c, float d) {
  union { bf16 h[4]; uint2 u; } t;
  t.h[0] = (bf16)a; t.h[1] = (bf16)b; t.h[2] = (bf16)c; t.h[3] = (bf16)d;
  *(uint2*)dst = t.u;
}

// async global->LDS, 16B per lane; lds base must be wave-uniform
__device__ inline void gl_lds16(const bf16* g, bf16* l) {
  __builtin_amdgcn_global_load_lds(
      (const __attribute__((address_space(1))) void*)g,
      (__attribute__((address_space(3))) void*)l, 16, 0, 0);
}

// ---------------- fp32 -> bf16 conversion ----------------
__global__ __launch_bounds__(256) void cvt_f32_bf16(
    const float* __restrict__ s, bf16* __restrict__ d, int n) {
  int i = (blockIdx.x * 256 + threadIdx.x) << 2;
  if (i >= n) return;
  float4 v = *(const float4*)(s + i);
  cvt_store4(d + i, v.x, v.y, v.z, v.w);
}

// wkv_a [576][2048] -> bf16 [640][2048], rows 576.. zeroed
__global__ __launch_bounds__(256) void cvt_pad_wkva(
    const float* __restrict__ s, bf16* __restrict__ d) {
  int i = (blockIdx.x * 256 + threadIdx.x) << 2;   // over 640*2048
  int r = i >> 11;
  if (r < 576) {
    float4 v = *(const float4*)(s + i);
    cvt_store4(d + i, v.x, v.y, v.z, v.w);
  } else {
    *(uint2*)(d + i) = make_uint2(0u, 0u);
  }
}

// ---------------- GEMM: C[M,N] = A[M,K] @ Bw[N,K]^T  (all bf16 in) ----------
// m97 structure: 128x128 tile, BK=64, unpadded LDS staged via global_load_lds
// width-16. M%128==0, N%128==0, K%64==0 required (inputs padded to satisfy).
// TRANS: C is bf16 vT[B][H][DV][SS] (N must be H*DV=2048, M=NTOK).
template <typename TC, bool TRANS>
__global__ __launch_bounds__(256) void gemm_bt_bf16(
    const bf16* __restrict__ A, const bf16* __restrict__ Bw, TC* __restrict__ C,
    int M, int N, int K) {
  __shared__ __align__(16) bf16 As[128 * 64];
  __shared__ __align__(16) bf16 Bs[128 * 64];
  const int tid  = threadIdx.x;
  const int wave = tid >> 6, lane = tid & 63;
  const int m0 = blockIdx.x << 7, n0 = blockIdx.y << 7;
  const int quad = lane >> 4, l16 = lane & 15;
  const int wm = (wave >> 1) << 6, wn = (wave & 1) << 6;
  const int srow = wave << 5;            // wave's 32-row staging block
  const int lrow = lane >> 3;            // +0..7
  const int lcol = (lane & 7) << 3;      // 0..56 elems

  const bf16* gA = A  + (size_t)(m0 + srow + lrow) * K + lcol;
  const bf16* gB = Bw + (size_t)(n0 + srow + lrow) * K + lcol;
  bf16* lA = As + srow * 64;
  bf16* lB = Bs + srow * 64;

  floatx4 acc[4][4];
#pragma unroll
  for (int i = 0; i < 4; i++)
#pragma unroll
    for (int j = 0; j < 4; j++) acc[i][j] = floatx4{0.f, 0.f, 0.f, 0.f};

  for (int k0 = 0; k0 < K; k0 += 64) {
    __syncthreads();                     // prev frag reads done
#pragma unroll
    for (int t = 0; t < 4; t++) {
      gl_lds16(gA + (size_t)(t << 3) * K + k0, lA + (t << 3) * 64);
      gl_lds16(gB + (size_t)(t << 3) * K + k0, lB + (t << 3) * 64);
    }
    __syncthreads();                     // drains vmcnt (m97 structure)
#pragma unroll
    for (int ks = 0; ks < 2; ks++) {
      bf16x8 af[4], bv[4];
#pragma unroll
      for (int i = 0; i < 4; i++)
        af[i] = *(const bf16x8*)&As[(wm + (i << 4) + l16) * 64 + (ks << 5) + (quad << 3)];
#pragma unroll
      for (int j = 0; j < 4; j++)
        bv[j] = *(const bf16x8*)&Bs[(wn + (j << 4) + l16) * 64 + (ks << 5) + (quad << 3)];
#pragma unroll
      for (int i = 0; i < 4; i++)
#pragma unroll
        for (int j = 0; j < 4; j++)
          acc[i][j] = __builtin_amdgcn_mfma_f32_16x16x32_bf16(af[i], bv[j], acc[i][j], 0, 0, 0);
    }
  }

  if constexpr (TRANS) {
    // lane owns rows gm..gm+3 (contiguous m) of col gn -> one 8B store
#pragma unroll
    for (int i = 0; i < 4; i++) {
      int gm = m0 + wm + (i << 4) + (quad << 2);
      int bb = gm >> 10, s = gm & 1023;
#pragma unroll
      for (int j = 0; j < 4; j++) {
        int gn = n0 + wn + (j << 4) + l16;
        int hh = gn >> 7, vd = gn & 127;
        union { bf16 h4[4]; uint2 u; } pk;
#pragma unroll
        for (int r = 0; r < 4; r++) pk.h4[r] = (bf16)acc[i][j][r];
        *(uint2*)((bf16*)C + ((((size_t)bb * HH + hh) * DV + vd) << 10) + s) = pk.u;
      }
    }
  } else {
#pragma unroll
    for (int i = 0; i < 4; i++)
#pragma unroll
      for (int j = 0; j < 4; j++) {
        int gn = n0 + wn + (j << 4) + l16;
#pragma unroll
        for (int r = 0; r < 4; r++) {
          int gm = m0 + wm + (i << 4) + (quad << 2) + r;
          C[(size_t)gm * N + gn] = (TC)acc[i][j][r];
        }
      }
  }
}

// ---------------- rmsnorm bf16 -> bf16 ----------------
__global__ __launch_bounds__(256) void rmsnorm_bf16(
    const bf16* __restrict__ in, int istride, const float* __restrict__ w,
    bf16* __restrict__ out, int L) {
  const int row = blockIdx.x;
  const bf16* p = in + (size_t)row * istride;
  float ss = 0.f;
  for (int c = threadIdx.x << 2; c < L; c += 1024) {
    union { uint2 u; bf16 h[4]; } t;
    t.u = *(const uint2*)(p + c);
#pragma unroll
    for (int r = 0; r < 4; r++) { float v = (float)t.h[r]; ss += v * v; }
  }
#pragma unroll
  for (int off = 32; off > 0; off >>= 1) ss += __shfl_down(ss, off);
  __shared__ float red[4];
  if ((threadIdx.x & 63) == 0) red[threadIdx.x >> 6] = ss;
  __syncthreads();
  float tot = red[0] + red[1] + red[2] + red[3];
  float rs = rsqrtf(tot / (float)L + EPSF);
  for (int c = threadIdx.x << 2; c < L; c += 1024) {
    union { uint2 u; bf16 h[4]; } t, o;
    t.u = *(const uint2*)(p + c);
#pragma unroll
    for (int r = 0; r < 4; r++) o.h[r] = (bf16)((float)t.h[r] * rs * w[c + r]);
    *(uint2*)(out + (size_t)row * L + c) = o.u;
  }
}

// ---------------- rope (interleaved, bf16 in/out) ----------------
__global__ void rope_q(bf16* __restrict__ q, const float* __restrict__ sin_t,
                       const float* __restrict__ cos_t) {
  int idx = blockIdx.x * 256 + threadIdx.x;   // NTOK*HH*32
  int i = idx & 31, h = (idx >> 5) & 15, row = idx >> 9;
  int pos = row & (SS - 1);
  bf16* base = q + ((size_t)row * HH + h) * DQK + DNOPE + (i << 1);
  union { uint u; bf16 h2[2]; } t;
  t.u = *(uint*)base;
  float e = (float)t.h2[0], o = (float)t.h2[1];
  float c = cos_t[(pos << 5) + i], s = sin_t[(pos << 5) + i];
  t.h2[0] = (bf16)(e * c - o * s);
  t.h2[1] = (bf16)(e * s + o * c);
  *(uint*)base = t.u;
}

__global__ void rope_k(const bf16* __restrict__ kvb, const float* __restrict__ sin_t,
                       const float* __restrict__ cos_t, bf16* __restrict__ kpe) {
  int idx = blockIdx.x * 256 + threadIdx.x;   // NTOK*32
  int i = idx & 31, row = idx >> 5;
  int pos = row & (SS - 1);
  union { uint u; bf16 h2[2]; } t;
  t.u = *(const uint*)(kvb + (size_t)row * 640 + KVLR + (i << 1));
  float e = (float)t.h2[0], o = (float)t.h2[1];
  float c = cos_t[(pos << 5) + i], s = sin_t[(pos << 5) + i];
  t.h2[0] = (bf16)(e * c - o * s);
  t.h2[1] = (bf16)(e * s + o * c);
  *(uint*)(kpe + (size_t)row * DROPE + (i << 1)) = t.u;
}

// ---------------- flash attention ----------------
// grid (S/64, H, B) with qt reversed for load balance; 4 waves, wave w owns
// q rows [w*16, w*16+16). Q frags hoisted to registers; V^T staged from vT.
__global__ __launch_bounds__(256) void attn_kernel(
    const bf16* __restrict__ q, const bf16* __restrict__ knope,
    const bf16* __restrict__ kpe, const bf16* __restrict__ vT,
    bf16* __restrict__ out) {
  const int qt = gridDim.x - 1 - blockIdx.x;
  const int q0 = qt << 6;
  const int h = blockIdx.y, b = blockIdx.z;
  __shared__ __align__(16) bf16 Ks[64][200];   // 192 pad->200 (2-way free)
  __shared__ __align__(16) bf16 Vts[128][72];  // V^T tile [vd][key]
  __shared__ __align__(16) bf16 Ps[4][16][72]; // per-wave P (pad 72)
  const int tid = threadIdx.x, wave = tid >> 6, lane = tid & 63;
  const int quad = lane >> 4, l16 = lane & 15;

  // stage Q (64x192) through Ks, pull A-frags to registers
  for (int i = tid; i < 64 * 24; i += 256) {
    int r = i / 24, c = (i % 24) << 3;
    *(uint4*)&Ks[r][c] =
        *(const uint4*)(q + ((size_t)((b << 10) + q0 + r) * HH + h) * DQK + c);
  }
  __syncthreads();
  bf16x8 aq[6];
#pragma unroll
  for (int t = 0; t < 6; t++)
    aq[t] = *(const bf16x8*)&Ks[(wave << 4) + l16][(t << 5) + (quad << 3)];

  floatx4 acc_o[8];
#pragma unroll
  for (int n = 0; n < 8; n++) acc_o[n] = floatx4{0.f, 0.f, 0.f, 0.f};
  float m_i[4], l_i[4];
#pragma unroll
  for (int r = 0; r < 4; r++) { m_i[r] = -1e30f; l_i[r] = 0.f; }

  const float scale = 0.07216878364870323f;   // 1/sqrt(192)

  for (int kt = 0; kt <= qt; kt++) {
    const int k0 = kt << 6;
    __syncthreads();   // prior LDS reads (aq on first iter / PV) done
    // stage K: cols 0..127 knope, 128..191 kpe
    for (int i = tid; i < 64 * 16; i += 256) {
      int r = i >> 4, c = (i & 15) << 3;
      *(uint4*)&Ks[r][c] =
          *(const uint4*)(knope + ((size_t)((b << 10) + k0 + r) * HH + h) * DNOPE + c);
    }
    for (int i = tid; i < 64 * 8; i += 256) {
      int r = i >> 3, c = (i & 7) << 3;
      *(uint4*)&Ks[r][DNOPE + c] =
          *(const uint4*)(kpe + (size_t)((b << 10) + k0 + r) * DROPE + c);
    }
    // stage V^T (coalesced from vT[b][h][vd][s])
    for (int i = tid; i < 128 * 8; i += 256) {
      int vd = i >> 3, c = (i & 7) << 3;
      *(uint4*)&Vts[vd][c] =
          *(const uint4*)(vT + ((((size_t)b * HH + h) * DV + vd) << 10) + k0 + c);
    }
    __syncthreads();

    // QK^T: wave computes 16(q) x 64(k)
    floatx4 sacc[4];
#pragma unroll
    for (int kn = 0; kn < 4; kn++) {
      floatx4 s = floatx4{0.f, 0.f, 0.f, 0.f};
#pragma unroll
      for (int t = 0; t < 6; t++) {
        bf16x8 bk = *(const bf16x8*)&Ks[(kn << 4) + l16][(t << 5) + (quad << 3)];
        s = __builtin_amdgcn_mfma_f32_16x16x32_bf16(aq[t], bk, s, 0, 0, 0);
      }
      sacc[kn] = s;
    }

    // scale + mask + online softmax (quad-local rows)
    float pv[4][4], mtile[4];
#pragma unroll
    for (int r = 0; r < 4; r++) mtile[r] = -1e30f;
#pragma unroll
    for (int kn = 0; kn < 4; kn++)
#pragma unroll
      for (int r = 0; r < 4; r++) {
        int qg = q0 + (wave << 4) + (quad << 2) + r;
        int kg = k0 + (kn << 4) + l16;
        float sv = sacc[kn][r] * scale;
        if (kg > qg) sv = -1e30f;
        pv[kn][r] = sv;
        mtile[r] = fmaxf(mtile[r], sv);
      }
#pragma unroll
    for (int r = 0; r < 4; r++) {
#pragma unroll
      for (int off = 1; off < 16; off <<= 1)
        mtile[r] = fmaxf(mtile[r], __shfl_xor(mtile[r], off));
    }
    float alpha[4];
#pragma unroll
    for (int r = 0; r < 4; r++) {
      float mnew = fmaxf(m_i[r], mtile[r]);
      alpha[r] = __expf(m_i[r] - mnew);
      m_i[r] = mnew;
      float part = 0.f;
#pragma unroll
      for (int kn = 0; kn < 4; kn++) {
        float p = __expf(pv[kn][r] - mnew);
        pv[kn][r] = p;
        part += p;
      }
#pragma unroll
      for (int off = 1; off < 16; off <<= 1) part += __shfl_xor(part, off);
      l_i[r] = l_i[r] * alpha[r] + part;
    }
    // P: C-layout regs -> LDS (own wave slice; no barrier needed)
#pragma unroll
    for (int kn = 0; kn < 4; kn++)
#pragma unroll
      for (int r = 0; r < 4; r++)
        Ps[wave][(quad << 2) + r][(kn << 4) + l16] = (bf16)pv[kn][r];
#pragma unroll
    for (int n = 0; n < 8; n++)
#pragma unroll
      for (int r = 0; r < 4; r++) acc_o[n][r] *= alpha[r];

    // PV: P(16x64) @ V(64x128)
    bf16x8 ap[2];
#pragma unroll
    for (int t = 0; t < 2; t++)
      ap[t] = *(const bf16x8*)&Ps[wave][l16][(t << 5) + (quad << 3)];
#pragma unroll
    for (int n = 0; n < 8; n++) {
#pragma unroll
      for (int t = 0; t < 2; t++) {
        bf16x8 bv = *(const bf16x8*)&Vts[(n << 4) + l16][(t << 5) + (quad << 3)];
        acc_o[n] = __builtin_amdgcn_mfma_f32_16x16x32_bf16(ap[t], bv, acc_o[n], 0, 0, 0);
      }
    }
  }

  // epilogue
#pragma unroll
  for (int r = 0; r < 4; r++) {
    float inv = 1.f / l_i[r];
    int qg = (b << 10) + q0 + (wave << 4) + (quad << 2) + r;
#pragma unroll
    for (int n = 0; n < 8; n++)
      out[((size_t)qg * HH + h) * DNOPE + (n << 4) + l16] = (bf16)(acc_o[n][r] * inv);
  }
}

// ---------------- launch ----------------
extern "C" void kernel_launch(void* const* d_in, const int* in_sizes, int n_in,
                              void* d_out, int out_size, void* d_ws, size_t ws_size,
                              hipStream_t stream) {
  (void)in_sizes; (void)n_in; (void)out_size; (void)ws_size;
  const float* x        = (const float*)d_in[0];
  const float* wq_a     = (const float*)d_in[1];
  const float* w_qa_ln  = (const float*)d_in[2];
  const float* wq_b     = (const float*)d_in[3];
  const float* wkv_a    = (const float*)d_in[4];
  const float* w_kva_ln = (const float*)d_in[5];
  const float* wk_b     = (const float*)d_in[6];
  const float* wv_b     = (const float*)d_in[7];
  const float* wo       = (const float*)d_in[8];
  const float* rsin     = (const float*)d_in[9];
  const float* rcos     = (const float*)d_in[10];
  float* out = (float*)d_out;

  // workspace layout (liveness-aliased), total 116.4 MB
  char* ws = (char*)d_ws;
  bf16* q     = (bf16*)(ws + 0);            // 25.17M  (steps q-gemm .. attn)
  bf16* xb    = (bf16*)(ws + 25165824);     // 16.78M  x bf16 (dead after kv gemm)
  bf16* knope = (bf16*)(ws + 25165824);     //         aliases xb
  bf16* qlat  = (bf16*)(ws + 41943040);     // 12.58M  (dead after rmsnorm)
  bf16* attnb = (bf16*)(ws + 41943040);     // 16.78M  aliases qlat
  bf16* qln   = (bf16*)(ws + 58720256);     // 12.58M  (dead after q gemm)
  bf16* vT    = (bf16*)(ws + 58720256);     // 16.78M  aliases qln
  bf16* kvb   = (bf16*)(ws + 75497472);     // 5.24M   [4096][640]
  bf16* wqbb  = (bf16*)(ws + 80740352);     // 9.44M
  bf16* wob   = (bf16*)(ws + 90177536);     // 8.39M
  bf16* wqab  = (bf16*)(ws + 98566144);     // 6.29M
  bf16* wkvab = (bf16*)(ws + 104857600);    // 2.62M   [640][2048] padded
  bf16* wkbb  = (bf16*)(ws + 107479040);    // 2.10M
  bf16* wvbb  = (bf16*)(ws + 109576192);    // 2.10M
  bf16* ckv   = (bf16*)(ws + 111673344);    // 4.19M
  bf16* kpe   = (bf16*)(ws + 115867648);    // 0.52M -> end 116391936

  dim3 blk(256);
  // convert inputs to bf16 once
  cvt_f32_bf16<<<8192, blk, 0, stream>>>(x,    xb,   8388608);
  cvt_f32_bf16<<<3072, blk, 0, stream>>>(wq_a, wqab, 3145728);
  cvt_f32_bf16<<<4608, blk, 0, stream>>>(wq_b, wqbb, 4718592);
  cvt_pad_wkva<<<1280, blk, 0, stream>>>(wkv_a, wkvab);
  cvt_f32_bf16<<<1024, blk, 0, stream>>>(wk_b, wkbb, 1048576);
  cvt_f32_bf16<<<1024, blk, 0, stream>>>(wv_b, wvbb, 1048576);
  cvt_f32_bf16<<<4096, blk, 0, stream>>>(wo,   wob,  4194304);

  gemm_bt_bf16<bf16, false><<<dim3(32, 12), blk, 0, stream>>>(xb, wqab, qlat, NTOK, QLR, HID);
  rmsnorm_bf16<<<NTOK, blk, 0, stream>>>(qlat, QLR, w_qa_ln, qln, QLR);
  gemm_bt_bf16<bf16, false><<<dim3(32, 24), blk, 0, stream>>>(qln, wqbb, q, NTOK, HH * DQK, QLR);
  gemm_bt_bf16<bf16, false><<<dim3(32, 5),  blk, 0, stream>>>(xb, wkvab, kvb, NTOK, 640, HID);
  rmsnorm_bf16<<<NTOK, blk, 0, stream>>>(kvb, 640, w_kva_ln, ckv, KVLR);
  rope_k<<<512,  blk, 0, stream>>>(kvb, rsin, rcos, kpe);
  rope_q<<<8192, blk, 0, stream>>>(q, rsin, rcos);
  gemm_bt_bf16<bf16, false><<<dim3(32, 16), blk, 0, stream>>>(ckv, wkbb, knope, NTOK, HH * DNOPE, KVLR);
  gemm_bt_bf16<bf16, true ><<<dim3(32, 16), blk, 0, stream>>>(ckv, wvbb, vT, NTOK, HH * DV, KVLR);
  attn_kernel<<<dim3(SS / 64, HH, BB), blk, 0, stream>>>(q, knope, kpe, vT, attnb);
  gemm_bt_bf16<float, false><<<dim3(32, 16), blk, 0, stream>>>(attnb, wob, out, NTOK, HID, HID);
}

// Round 4
// 550.277 us; speedup vs baseline: 2.3791x; 1.0701x over previous
//
#include <hip/hip_runtime.h>
#include <stdint.h>

typedef __bf16 bf16;
typedef __bf16 bf16x8 __attribute__((ext_vector_type(8)));
typedef float floatx4 __attribute__((ext_vector_type(4)));

#define HH     16
#define DNOPE  128
#define DROPE  64
#define DV     128
#define DQK    192
#define HID    2048
#define QLR    1536
#define KVLR   512
#define BB     4
#define SS     1024
#define NTOK   4096
#define XOUTW  2176     // merged first-gemm output width (1536 qlat + 640 kv)
#define EPSF   1e-6f

// ---------------- helpers ----------------
__device__ inline void cvt_store4(bf16* dst, float a, float b, float c, float d) {
  union { bf16 h[4]; uint2 u; } t;
  t.h[0] = (bf16)a; t.h[1] = (bf16)b; t.h[2] = (bf16)c; t.h[3] = (bf16)d;
  *(uint2*)dst = t.u;
}

__device__ inline void gl_lds16(const bf16* g, bf16* l) {
  __builtin_amdgcn_global_load_lds(
      (const __attribute__((address_space(1))) void*)g,
      (__attribute__((address_space(3))) void*)l, 16, 0, 0);
}

// ---------------- fp32 -> bf16 conversion (optional scale) ----------------
__global__ __launch_bounds__(256) void cvt_f32_bf16(
    const float* __restrict__ s, bf16* __restrict__ d, int n, float scale) {
  int i = (blockIdx.x * 256 + threadIdx.x) << 2;
  if (i >= n) return;
  float4 v = *(const float4*)(s + i);
  cvt_store4(d + i, v.x * scale, v.y * scale, v.z * scale, v.w * scale);
}

// wkv_a [576][2048] -> bf16 [640][2048] at dst, rows 576.. zeroed
__global__ __launch_bounds__(256) void cvt_pad_wkva(
    const float* __restrict__ s, bf16* __restrict__ d) {
  int i = (blockIdx.x * 256 + threadIdx.x) << 2;   // over 640*2048
  int r = i >> 11;
  if (r < 576) {
    float4 v = *(const float4*)(s + i);
    cvt_store4(d + i, v.x, v.y, v.z, v.w);
  } else {
    *(uint2*)(d + i) = make_uint2(0u, 0u);
  }
}

// ---------------- GEMM: C[M,N] = A[M,K] @ Bw[N,K]^T (all bf16 in) ----------
// m97 structure: 128x128 tile, BK=64, LDS staged via global_load_lds w=16.
// EPI 0: normal store to C0 (row stride N).
// EPI 1: n<2048 -> C0 with ROW STRIDE 2048 (knope [4096][2048]);
//        n>=2048 -> C1 as vT[b][h][dv][s] with 8B packed stores.
template <typename TC, int EPI>
__global__ __launch_bounds__(256) void gemm_bt_bf16(
    const bf16* __restrict__ A, const bf16* __restrict__ Bw,
    TC* __restrict__ C0, bf16* __restrict__ C1, int M, int N, int K) {
  __shared__ __align__(16) bf16 As[128 * 64];
  __shared__ __align__(16) bf16 Bs[128 * 64];
  const int tid  = threadIdx.x;
  const int wave = tid >> 6, lane = tid & 63;
  const int m0 = blockIdx.x << 7, n0 = blockIdx.y << 7;
  const int quad = lane >> 4, l16 = lane & 15;
  const int wm = (wave >> 1) << 6, wn = (wave & 1) << 6;
  const int srow = wave << 5;
  const int lrow = lane >> 3;
  const int lcol = (lane & 7) << 3;

  const bf16* gA = A  + (size_t)(m0 + srow + lrow) * K + lcol;
  const bf16* gB = Bw + (size_t)(n0 + srow + lrow) * K + lcol;
  bf16* lA = As + srow * 64;
  bf16* lB = Bs + srow * 64;

  floatx4 acc[4][4];
#pragma unroll
  for (int i = 0; i < 4; i++)
#pragma unroll
    for (int j = 0; j < 4; j++) acc[i][j] = floatx4{0.f, 0.f, 0.f, 0.f};

  for (int k0 = 0; k0 < K; k0 += 64) {
    __syncthreads();
#pragma unroll
    for (int t = 0; t < 4; t++) {
      gl_lds16(gA + (size_t)(t << 3) * K + k0, lA + (t << 3) * 64);
      gl_lds16(gB + (size_t)(t << 3) * K + k0, lB + (t << 3) * 64);
    }
    __syncthreads();
#pragma unroll
    for (int ks = 0; ks < 2; ks++) {
      bf16x8 af[4], bv[4];
#pragma unroll
      for (int i = 0; i < 4; i++)
        af[i] = *(const bf16x8*)&As[(wm + (i << 4) + l16) * 64 + (ks << 5) + (quad << 3)];
#pragma unroll
      for (int j = 0; j < 4; j++)
        bv[j] = *(const bf16x8*)&Bs[(wn + (j << 4) + l16) * 64 + (ks << 5) + (quad << 3)];
#pragma unroll
      for (int i = 0; i < 4; i++)
#pragma unroll
        for (int j = 0; j < 4; j++)
          acc[i][j] = __builtin_amdgcn_mfma_f32_16x16x32_bf16(af[i], bv[j], acc[i][j], 0, 0, 0);
    }
  }

  if constexpr (EPI == 1) {
    if (n0 >= 2048) {
      // vT epilogue: lane holds 4 contiguous m for col gn -> one 8B store
#pragma unroll
      for (int i = 0; i < 4; i++) {
        int gm = m0 + wm + (i << 4) + (quad << 2);
        int bb = gm >> 10, s = gm & 1023;
#pragma unroll
        for (int j = 0; j < 4; j++) {
          int gn = n0 + wn + (j << 4) + l16 - 2048;
          int hh = gn >> 7, vd = gn & 127;
          union { bf16 h4[4]; uint2 u; } pk;
#pragma unroll
          for (int r = 0; r < 4; r++) pk.h4[r] = (bf16)acc[i][j][r];
          *(uint2*)(C1 + ((((size_t)bb * HH + hh) * DV + vd) << 10) + s) = pk.u;
        }
      }
      return;
    }
  }
  // FIX (R3): knope output row stride is 2048, not the merged logical N=4096.
  const int ldc = (EPI == 1) ? 2048 : N;
#pragma unroll
  for (int i = 0; i < 4; i++)
#pragma unroll
    for (int j = 0; j < 4; j++) {
      int gn = n0 + wn + (j << 4) + l16;
#pragma unroll
      for (int r = 0; r < 4; r++) {
        int gm = m0 + wm + (i << 4) + (quad << 2) + r;
        C0[(size_t)gm * ldc + gn] = (TC)acc[i][j][r];
      }
    }
}

// ---------------- rmsnorm bf16 -> bf16 ----------------
__global__ __launch_bounds__(256) void rmsnorm_bf16(
    const bf16* __restrict__ in, int istride, const float* __restrict__ w,
    bf16* __restrict__ out, int L) {
  const int row = blockIdx.x;
  const bf16* p = in + (size_t)row * istride;
  float ss = 0.f;
  for (int c = threadIdx.x << 2; c < L; c += 1024) {
    union { uint2 u; bf16 h[4]; } t;
    t.u = *(const uint2*)(p + c);
#pragma unroll
    for (int r = 0; r < 4; r++) { float v = (float)t.h[r]; ss += v * v; }
  }
#pragma unroll
  for (int off = 32; off > 0; off >>= 1) ss += __shfl_down(ss, off);
  __shared__ float red[4];
  if ((threadIdx.x & 63) == 0) red[threadIdx.x >> 6] = ss;
  __syncthreads();
  float tot = red[0] + red[1] + red[2] + red[3];
  float rs = rsqrtf(tot / (float)L + EPSF);
  for (int c = threadIdx.x << 2; c < L; c += 1024) {
    union { uint2 u; bf16 h[4]; } t, o;
    t.u = *(const uint2*)(p + c);
#pragma unroll
    for (int r = 0; r < 4; r++) o.h[r] = (bf16)((float)t.h[r] * rs * w[c + r]);
    *(uint2*)(out + (size_t)row * L + c) = o.u;
  }
}

// ---------------- rope (interleaved, bf16 in/out) ----------------
__global__ void rope_q(bf16* __restrict__ q, const float* __restrict__ sin_t,
                       const float* __restrict__ cos_t) {
  int idx = blockIdx.x * 256 + threadIdx.x;   // NTOK*HH*32
  int i = idx & 31, h = (idx >> 5) & 15, row = idx >> 9;
  int pos = row & (SS - 1);
  bf16* base = q + ((size_t)row * HH + h) * DQK + DNOPE + (i << 1);
  union { uint u; bf16 h2[2]; } t;
  t.u = *(uint*)base;
  float e = (float)t.h2[0], o = (float)t.h2[1];
  float c = cos_t[(pos << 5) + i], s = sin_t[(pos << 5) + i];
  t.h2[0] = (bf16)(e * c - o * s);
  t.h2[1] = (bf16)(e * s + o * c);
  *(uint*)base = t.u;
}

__global__ void rope_k(const bf16* __restrict__ xout, const float* __restrict__ sin_t,
                       const float* __restrict__ cos_t, bf16* __restrict__ kpe) {
  int idx = blockIdx.x * 256 + threadIdx.x;   // NTOK*32
  int i = idx & 31, row = idx >> 5;
  int pos = row & (SS - 1);
  union { uint u; bf16 h2[2]; } t;
  t.u = *(const uint*)(xout + (size_t)row * XOUTW + QLR + KVLR + (i << 1));
  float e = (float)t.h2[0], o = (float)t.h2[1];
  float c = cos_t[(pos << 5) + i], s = sin_t[(pos << 5) + i];
  t.h2[0] = (bf16)(e * c - o * s);
  t.h2[1] = (bf16)(e * s + o * c);
  *(uint*)(kpe + (size_t)row * DROPE + (i << 1)) = t.u;
}

// ---------------- flash attention ----------------
// grid (S/128, H, B) reversed-qt; 512 thr = 8 waves, wave w owns q rows
// [w*16, w*16+16). Q frags in regs (staged via Ks in 2 rounds). Per 64-key
// tile: reg-prefetched K/V staging, QK^T MFMA, exp2-domain online softmax
// (scale*log2e folded into wq_b), P->LDS, O^T = V^T * P^T MFMA.
__global__ __launch_bounds__(512, 4) void attn_kernel(
    const bf16* __restrict__ q, const bf16* __restrict__ knope,
    const bf16* __restrict__ kpe, const bf16* __restrict__ vT,
    bf16* __restrict__ out) {
  const int qt = gridDim.x - 1 - blockIdx.x;   // 0..7
  const int q0 = qt << 7;
  const int h = blockIdx.y, b = blockIdx.z;
  __shared__ __align__(16) bf16 Ks[64][200];   // K tile (192 pad 200)
  __shared__ __align__(16) bf16 Vts[128][72];  // V^T tile [dv][key]
  __shared__ __align__(16) bf16 Ps[8][16][72]; // per-wave P [q][k]
  __shared__ float alphaS[8][16];
  __shared__ float invlS[8][16];
  const int tid = threadIdx.x, wave = tid >> 6, lane = tid & 63;
  const int quad = lane >> 4, l16 = lane & 15;

  // ---- Q fragments: two staging rounds through Ks ----
  bf16x8 aq[6];
  for (int round = 0; round < 2; round++) {
    __syncthreads();
    for (int i = tid; i < 64 * 24; i += 512) {
      int r = i / 24, c = (i % 24) << 3;
      *(uint4*)&Ks[r][c] = *(const uint4*)(
          q + ((size_t)((b << 10) + q0 + (round << 6) + r) * HH + h) * DQK + c);
    }
    __syncthreads();
    if ((wave >> 2) == round) {
      int rw = wave & 3;
#pragma unroll
      for (int t = 0; t < 6; t++)
        aq[t] = *(const bf16x8*)&Ks[(rw << 4) + l16][(t << 5) + (quad << 3)];
    }
  }

  // per-thread staging coordinates
  const int knr = tid >> 4;              // 0..31 (+32)
  const int knc = (tid & 15) << 3;
  const int kpr = tid >> 3;              // 0..63
  const int kpc = (tid & 7) << 3;
  const int vtr = tid >> 3;              // 0..63 (+64)
  const int vtc = (tid & 7) << 3;
  const bf16* knbase = knope + ((size_t)((b << 10) + knr) * HH + h) * DNOPE + knc;
  const bf16* kpbase = kpe + (size_t)((b << 10) + kpr) * DROPE + kpc;
  const bf16* vtbase = vT + ((((size_t)b * HH + h) * DV + vtr) << 10) + vtc;

  const int nkt = (qt << 1) + 2;
  uint4 pk0, pk1, pp0, pv0, pv1;
  pk0 = *(const uint4*)(knbase);
  pk1 = *(const uint4*)(knbase + (size_t)32 * HH * DNOPE);
  pp0 = *(const uint4*)(kpbase);
  pv0 = *(const uint4*)(vtbase);
  pv1 = *(const uint4*)(vtbase + ((size_t)64 << 10));

  floatx4 acc_o[8];
#pragma unroll
  for (int n = 0; n < 8; n++) acc_o[n] = floatx4{0.f, 0.f, 0.f, 0.f};
  float m_i[4], l_i[4];
#pragma unroll
  for (int r = 0; r < 4; r++) { m_i[r] = -1e30f; l_i[r] = 0.f; }

  for (int kt = 0; kt < nkt; kt++) {
    const int k0 = kt << 6;
    __syncthreads();                 // prev LDS reads done
    *(uint4*)&Ks[knr][knc] = pk0;
    *(uint4*)&Ks[32 + knr][knc] = pk1;
    *(uint4*)&Ks[kpr][DNOPE + kpc] = pp0;
    *(uint4*)&Vts[vtr][vtc] = pv0;
    *(uint4*)&Vts[64 + vtr][vtc] = pv1;
    if (kt + 1 < nkt) {              // prefetch next tile into regs
      size_t ko = (size_t)(kt + 1) << 6;
      pk0 = *(const uint4*)(knbase + ko * HH * DNOPE);
      pk1 = *(const uint4*)(knbase + (ko + 32) * HH * DNOPE);
      pp0 = *(const uint4*)(kpbase + ko * DROPE);
      pv0 = *(const uint4*)(vtbase + ko);
      pv1 = *(const uint4*)(vtbase + ko + ((size_t)64 << 10));
    }
    __syncthreads();

    // QK^T: 16(q) x 64(k) per wave; scores pre-scaled by scale*log2e via wq_b
    floatx4 sacc[4];
#pragma unroll
    for (int kn = 0; kn < 4; kn++) {
      floatx4 s = floatx4{0.f, 0.f, 0.f, 0.f};
#pragma unroll
      for (int t = 0; t < 6; t++) {
        bf16x8 bk = *(const bf16x8*)&Ks[(kn << 4) + l16][(t << 5) + (quad << 3)];
        s = __builtin_amdgcn_mfma_f32_16x16x32_bf16(aq[t], bk, s, 0, 0, 0);
      }
      sacc[kn] = s;
    }

    // extract + (diagonal-only) mask + row max
    float pvv[4][4], mtile[4];
#pragma unroll
    for (int r = 0; r < 4; r++) mtile[r] = -1e30f;
    if (kt >= (qt << 1)) {
#pragma unroll
      for (int kn = 0; kn < 4; kn++)
#pragma unroll
        for (int r = 0; r < 4; r++) {
          int qg = q0 + (wave << 4) + (quad << 2) + r;
          int kg = k0 + (kn << 4) + l16;
          float sv = sacc[kn][r];
          if (kg > qg) sv = -1e30f;
          pvv[kn][r] = sv;
          mtile[r] = fmaxf(mtile[r], sv);
        }
    } else {
#pragma unroll
      for (int kn = 0; kn < 4; kn++)
#pragma unroll
        for (int r = 0; r < 4; r++) {
          float sv = sacc[kn][r];
          pvv[kn][r] = sv;
          mtile[r] = fmaxf(mtile[r], sv);
        }
    }

    float alpha[4];
#pragma unroll
    for (int r = 0; r < 4; r++) {
#pragma unroll
      for (int off = 1; off < 16; off <<= 1)
        mtile[r] = fmaxf(mtile[r], __shfl_xor(mtile[r], off));
      float mnew = fmaxf(m_i[r], mtile[r]);
      alpha[r] = exp2f(m_i[r] - mnew);
      m_i[r] = mnew;
      float part = 0.f;
#pragma unroll
      for (int kn = 0; kn < 4; kn++) {
        float p = exp2f(pvv[kn][r] - mnew);
        pvv[kn][r] = p;
        part += p;
      }
#pragma unroll
      for (int off = 1; off < 16; off <<= 1) part += __shfl_xor(part, off);
      l_i[r] = l_i[r] * alpha[r] + part;
    }
    // P -> LDS (wave-private slice, no barrier)
#pragma unroll
    for (int kn = 0; kn < 4; kn++)
#pragma unroll
      for (int r = 0; r < 4; r++)
        Ps[wave][(quad << 2) + r][(kn << 4) + l16] = (bf16)pvv[kn][r];
    // broadcast alpha by q-row for the O^T (col = q) rescale
    if (l16 == 0)
      *(float4*)&alphaS[wave][quad << 2] =
          make_float4(alpha[0], alpha[1], alpha[2], alpha[3]);
    float alpha_lane = alphaS[wave][l16];
#pragma unroll
    for (int n = 0; n < 8; n++)
#pragma unroll
      for (int r = 0; r < 4; r++) acc_o[n][r] *= alpha_lane;

    // O^T += V^T(128xk) * P^T(kx16): A = V^T frags, B = P frags
    bf16x8 bp[2];
#pragma unroll
    for (int t = 0; t < 2; t++)
      bp[t] = *(const bf16x8*)&Ps[wave][l16][(t << 5) + (quad << 3)];
#pragma unroll
    for (int n = 0; n < 8; n++) {
#pragma unroll
      for (int t = 0; t < 2; t++) {
        bf16x8 av = *(const bf16x8*)&Vts[(n << 4) + l16][(t << 5) + (quad << 3)];
        acc_o[n] = __builtin_amdgcn_mfma_f32_16x16x32_bf16(av, bp[t], acc_o[n], 0, 0, 0);
      }
    }
  }

  // epilogue: O^T C-layout -> lane holds q=l16, dv = n*16+quad*4+r (packed 8B)
  if (l16 == 0)
    *(float4*)&invlS[wave][quad << 2] =
        make_float4(1.f / l_i[0], 1.f / l_i[1], 1.f / l_i[2], 1.f / l_i[3]);
  float invl = invlS[wave][l16];
  int tok = (b << 10) + q0 + (wave << 4) + l16;
  bf16* obase = out + ((size_t)tok * HH + h) * DV + (quad << 2);
#pragma unroll
  for (int n = 0; n < 8; n++) {
    union { bf16 h4[4]; uint2 u; } pk;
#pragma unroll
    for (int r = 0; r < 4; r++) pk.h4[r] = (bf16)(acc_o[n][r] * invl);
    *(uint2*)(obase + (n << 4)) = pk.u;
  }
}

// ---------------- launch ----------------
extern "C" void kernel_launch(void* const* d_in, const int* in_sizes, int n_in,
                              void* d_out, int out_size, void* d_ws, size_t ws_size,
                              hipStream_t stream) {
  (void)in_sizes; (void)n_in; (void)out_size; (void)ws_size;
  const float* x        = (const float*)d_in[0];
  const float* wq_a     = (const float*)d_in[1];
  const float* w_qa_ln  = (const float*)d_in[2];
  const float* wq_b     = (const float*)d_in[3];
  const float* wkv_a    = (const float*)d_in[4];
  const float* w_kva_ln = (const float*)d_in[5];
  const float* wk_b     = (const float*)d_in[6];
  const float* wv_b     = (const float*)d_in[7];
  const float* wo       = (const float*)d_in[8];
  const float* rsin     = (const float*)d_in[9];
  const float* rcos     = (const float*)d_in[10];
  float* out = (float*)d_out;

  // workspace (liveness-aliased), total ~112.2 MB
  char* ws = (char*)d_ws;
  bf16* xb    = (bf16*)(ws + 0);            // 16.78M, dead after xout gemm
  bf16* attnb = (bf16*)(ws + 0);            //   aliases xb
  bf16* xout  = (bf16*)(ws + 16777216);     // 17.83M [4096][2176]
  bf16* knope = (bf16*)(ws + 16777216);     //   aliases xout (dead by then), 16.78M stride 2048
  bf16* q     = (bf16*)(ws + 34603008);     // 25.17M
  bf16* qln   = (bf16*)(ws + 59768832);     // 12.58M, dead after q gemm
  bf16* vT    = (bf16*)(ws + 59768832);     //   aliases qln
  bf16* wA    = (bf16*)(ws + 76546048);     // 8.91M  [2176][2048]
  bf16* wqbb  = (bf16*)(ws + 85458944);     // 9.44M
  bf16* wkvB  = (bf16*)(ws + 94896128);     // 4.19M  [4096][512]
  bf16* wob   = (bf16*)(ws + 99090432);     // 8.39M
  bf16* ckv   = (bf16*)(ws + 107479040);    // 4.19M
  bf16* kpe   = (bf16*)(ws + 111673344);    // 0.52M -> end 112197632

  const float SCALEQ = (1.0f / sqrtf(192.0f)) * 1.44269504088896f; // into wq_b

  dim3 blk(256);
  cvt_f32_bf16<<<8192, blk, 0, stream>>>(x,    xb,   8388608, 1.0f);
  cvt_f32_bf16<<<3072, blk, 0, stream>>>(wq_a, wA,   3145728, 1.0f);
  cvt_pad_wkva<<<1280, blk, 0, stream>>>(wkv_a, wA + 3145728);
  cvt_f32_bf16<<<4608, blk, 0, stream>>>(wq_b, wqbb, 4718592, SCALEQ);
  cvt_f32_bf16<<<1024, blk, 0, stream>>>(wk_b, wkvB, 1048576, 1.0f);
  cvt_f32_bf16<<<1024, blk, 0, stream>>>(wv_b, wkvB + 1048576, 1048576, 1.0f);
  cvt_f32_bf16<<<4096, blk, 0, stream>>>(wo,   wob,  4194304, 1.0f);

  // xout = xb @ [wq_a ; wkv_a]^T   (cols 0..1535 qlat, 1536..2175 kv)
  gemm_bt_bf16<bf16, 0><<<dim3(32, 17), blk, 0, stream>>>(
      xb, wA, xout, nullptr, NTOK, XOUTW, HID);
  rmsnorm_bf16<<<NTOK, blk, 0, stream>>>(xout, XOUTW, w_qa_ln, qln, QLR);
  rmsnorm_bf16<<<NTOK, blk, 0, stream>>>(xout + QLR, XOUTW, w_kva_ln, ckv, KVLR);
  rope_k<<<512, blk, 0, stream>>>(xout, rsin, rcos, kpe);
  // q = qln @ wq_b^T  (pre-scaled by SCALEQ)
  gemm_bt_bf16<bf16, 0><<<dim3(32, 24), blk, 0, stream>>>(
      qln, wqbb, q, nullptr, NTOK, HH * DQK, QLR);
  rope_q<<<8192, blk, 0, stream>>>(q, rsin, rcos);
  // [knope | vT] = ckv @ [wk_b ; wv_b]^T   (dual epilogue)
  gemm_bt_bf16<bf16, 1><<<dim3(32, 32), blk, 0, stream>>>(
      ckv, wkvB, knope, vT, NTOK, 4096, KVLR);
  attn_kernel<<<dim3(SS / 128, HH, BB), dim3(512), 0, stream>>>(
      q, knope, kpe, vT, attnb);
  gemm_bt_bf16<float, 0><<<dim3(32, 16), blk, 0, stream>>>(
      attnb, wob, out, nullptr, NTOK, HID, HID);
}